// Round 8
// baseline (411.605 us; speedup 1.0000x reference)
//
#include <hip/hip_runtime.h>
#include <hip/hip_bf16.h>

#define N_NODES 50000
#define N_EDGES 800000
#define IN_DIM  256
#define OUT_DIM 64
#define NCH     49    // ceil(50000/1024) scan chunks
#define NB_SC   3125  // 800000/256 scatter blocks

using bf16x8 = __attribute__((ext_vector_type(8))) __bf16;
using f32x4  = __attribute__((ext_vector_type(4))) float;
using u16x8  = __attribute__((ext_vector_type(8))) unsigned short;

// ---------------------------------------------------------------------------
// Inline edge-dtype probe (int64 vs int32), block-uniform result.
// ---------------------------------------------------------------------------
__device__ __forceinline__ int probe_is64(const void* edges, int* nz_s) {
    if (threadIdx.x == 0) *nz_s = 0;
    __syncthreads();
    if (((const unsigned int*)edges)[2 * threadIdx.x + 1] != 0u) *nz_s = 1;
    __syncthreads();
    return (*nz_s == 0);
}

// cnt[dst]++ per edge
__global__ void deg_count(const void* __restrict__ edges, int* __restrict__ cnt) {
    __shared__ int nz;
    int is64 = probe_is64(edges, &nz);
    int e = blockIdx.x * 256 + threadIdx.x;
    if (e >= N_EDGES) return;
    int d = is64 ? (int)((const long long*)edges)[(long long)N_EDGES + e]
                 : ((const int*)edges)[(long long)N_EDGES + e];
    atomicAdd(&cnt[d], 1);
}

// --------------------- hierarchical exclusive scan -------------------------
__global__ __launch_bounds__(1024) void scan_local(const int* __restrict__ cnt,
                                                   int* __restrict__ off,
                                                   int* __restrict__ partial,
                                                   float* __restrict__ dinv) {
    __shared__ int smem[1024];
    int i = blockIdx.x * 1024 + threadIdx.x;
    int v = (i < N_NODES) ? cnt[i] : 0;
    if (i < N_NODES) dinv[i] = rsqrtf((float)(v + 1));
    smem[threadIdx.x] = v;
    __syncthreads();
    for (int s = 1; s < 1024; s <<= 1) {
        int t = 0;
        if (threadIdx.x >= s) t = smem[threadIdx.x - s];
        __syncthreads();
        if (threadIdx.x >= s) smem[threadIdx.x] += t;
        __syncthreads();
    }
    int incl = smem[threadIdx.x];
    if (i < N_NODES) off[i] = incl - v;
    if (threadIdx.x == 1023) partial[blockIdx.x] = incl;
}

__global__ void scan_mid(int* __restrict__ partial) {
    int lane = threadIdx.x;
    int v = (lane < NCH) ? partial[lane] : 0;
    int orig = v;
    for (int s = 1; s < 64; s <<= 1) {
        int t = __shfl_up(v, s);
        if (lane >= s) v += t;
    }
    if (lane < NCH) partial[lane] = v - orig;
    if (lane == 63) partial[63] = v;
}

__global__ __launch_bounds__(1024) void scan_add(int* __restrict__ off,
                                                 const int* __restrict__ partial,
                                                 int* __restrict__ cursor) {
    int i = blockIdx.x * 1024 + threadIdx.x;
    if (i < N_NODES) {
        int o = off[i] + partial[blockIdx.x];
        off[i] = o;
        cursor[i] = o;
    }
    if (i == 0) off[N_NODES] = partial[63];
}

// ---------------------------------------------------------------------------
// MFMA split-bf16 GEMM body: H[N,64] = X[N,K] @ W[K,64], f32 in/out.
// x = hi + lo (bf16 pair); X@W = hi_a*hi_b + hi_a*lo_b + lo_a*hi_b (3 MFMA).
// 256 threads = 4 waves; block covers 64 rows; wave w owns col slice
// [w*16, w*16+16). Per wave: 4 row-tiles (m), B-frags in registers.
// 16x16x32 layouts: A row = lane&15, k = (lane>>4)*8 + j (j in-lane);
// B col = lane&15, same k map (in-lane permutation cancels between A and B);
// D col = lane&15, row = (lane>>4)*4 + reg (m89-verified).
// ---------------------------------------------------------------------------
__device__ __forceinline__ unsigned short bf16_rn(float x) {
    unsigned u = __float_as_uint(x);
    unsigned r = u + 0x7FFFu + ((u >> 16) & 1u);
    return (unsigned short)(r >> 16);
}

template <int K>
__device__ __forceinline__ void gemm_body(int gbid, const float* __restrict__ X,
                                          const float* __restrict__ W,
                                          float* __restrict__ H) {
    constexpr int NS = K / 32;
    const int lane = threadIdx.x & 63;
    const int wave = threadIdx.x >> 6;   // col tile 0..3
    const int lm   = lane & 15;
    const int kg   = lane >> 4;          // 0..3

    // B fragments (this wave's 16 cols), hi/lo split, registers only.
    bf16x8 bhi[NS], blo[NS];
#pragma unroll
    for (int s = 0; s < NS; ++s) {
        u16x8 hb, lb;
#pragma unroll
        for (int j = 0; j < 8; ++j) {
            float w = W[(size_t)(s * 32 + kg * 8 + j) * 64 + wave * 16 + lm];
            unsigned short h = bf16_rn(w);
            float res = w - __uint_as_float((unsigned)h << 16);
            hb[j] = h;
            lb[j] = bf16_rn(res);
        }
        union { u16x8 u; bf16x8 b; } ch, cl;
        ch.u = hb; cl.u = lb;
        bhi[s] = ch.b; blo[s] = cl.b;
    }

    const int r0 = gbid * 64;
    const float* xr[4];
#pragma unroll
    for (int m = 0; m < 4; ++m) {
        int r = r0 + m * 16 + lm;
        xr[m] = X + (size_t)((r < N_NODES) ? r : (N_NODES - 1)) * K;
    }

    f32x4 acc[4] = {};

#pragma unroll 2
    for (int s = 0; s < NS; ++s) {
#pragma unroll
        for (int m = 0; m < 4; ++m) {
            float4 a0 = *(const float4*)(xr[m] + s * 32 + kg * 8);
            float4 a1 = *(const float4*)(xr[m] + s * 32 + kg * 8 + 4);
            float av[8] = {a0.x, a0.y, a0.z, a0.w, a1.x, a1.y, a1.z, a1.w};
            u16x8 ha, la;
#pragma unroll
            for (int j = 0; j < 8; ++j) {
                unsigned short h = bf16_rn(av[j]);
                float res = av[j] - __uint_as_float((unsigned)h << 16);
                ha[j] = h;
                la[j] = bf16_rn(res);
            }
            union { u16x8 u; bf16x8 b; } ah, al;
            ah.u = ha; al.u = la;
            acc[m] = __builtin_amdgcn_mfma_f32_16x16x32_bf16(ah.b, bhi[s], acc[m], 0, 0, 0);
            acc[m] = __builtin_amdgcn_mfma_f32_16x16x32_bf16(ah.b, blo[s], acc[m], 0, 0, 0);
            acc[m] = __builtin_amdgcn_mfma_f32_16x16x32_bf16(al.b, bhi[s], acc[m], 0, 0, 0);
        }
    }

    const int c = wave * 16 + lm;
#pragma unroll
    for (int m = 0; m < 4; ++m) {
#pragma unroll
        for (int t = 0; t < 4; ++t) {
            int r = r0 + m * 16 + kg * 4 + t;
            if (r < N_NODES) H[(size_t)r * 64 + c] = acc[m][t];
        }
    }
}

// ---------------------------------------------------------------------------
// Fused: blocks [0, nsc) scatter edges into CSR (HBM-write-bound, idle VALU);
// blocks [nsc, ...) run gemm1 (compute-bound). Overlap hides gemm1.
// ---------------------------------------------------------------------------
template <int K>
__global__ __launch_bounds__(256) void fused_scatter_gemm(const void* __restrict__ edges,
                                                          int* __restrict__ cursor,
                                                          int* __restrict__ csr_src,
                                                          const float* __restrict__ X,
                                                          const float* __restrict__ W,
                                                          float* __restrict__ H,
                                                          int nsc) {
    if ((int)blockIdx.x < nsc) {
        __shared__ int nz;
        int is64 = probe_is64(edges, &nz);
        int e = blockIdx.x * 256 + threadIdx.x;
        if (e >= N_EDGES) return;
        int s, d;
        if (is64) {
            s = (int)((const long long*)edges)[e];
            d = (int)((const long long*)edges)[(long long)N_EDGES + e];
        } else {
            s = ((const int*)edges)[e];
            d = ((const int*)edges)[(long long)N_EDGES + e];
        }
        int pos = atomicAdd(&cursor[d], 1);
        csr_src[pos] = s;
    } else {
        gemm_body<K>((int)blockIdx.x - nsc, X, W, H);
    }
}

template <int K>
__global__ __launch_bounds__(256) void gemm_mfma(const float* __restrict__ X,
                                                 const float* __restrict__ W,
                                                 float* __restrict__ H) {
    gemm_body<K>((int)blockIdx.x, X, W, H);
}

// ---------------------------------------------------------------------------
// Gather-aggregate: one wave per dst node, lane = column.
// out = relu( (Σ_s H[s]*dinv[s] + H[d]*dd) * dd + b )
// ---------------------------------------------------------------------------
__global__ __launch_bounds__(256) void agg_csr(const float* __restrict__ H,
                                               const float* __restrict__ dinv,
                                               const float* __restrict__ b,
                                               const int* __restrict__ off,
                                               const int* __restrict__ csr_src,
                                               float* __restrict__ out) {
    int wid  = (blockIdx.x * 256 + threadIdx.x) >> 6;
    int lane = threadIdx.x & 63;
    if (wid >= N_NODES) return;
    float dd = dinv[wid];
    float acc = H[(size_t)wid * 64 + lane] * dd;
    int beg = off[wid], end = off[wid + 1];
    for (int k0 = beg; k0 < end; k0 += 64) {
        int myk = k0 + lane;
        int   s_l  = (myk < end) ? csr_src[myk] : 0;
        float ds_l = (myk < end) ? dinv[s_l] : 0.f;
        int cnt = min(64, end - k0);
        int i = 0;
        for (; i + 8 <= cnt; i += 8) {
            float v[8], nm[8];
#pragma unroll
            for (int jj = 0; jj < 8; ++jj) {
                int s  = __shfl(s_l, i + jj);
                nm[jj] = __shfl(ds_l, i + jj);
                v[jj]  = H[(size_t)s * 64 + lane];
            }
#pragma unroll
            for (int jj = 0; jj < 8; ++jj) acc = fmaf(v[jj], nm[jj], acc);
        }
        for (; i < cnt; ++i) {
            int   s  = __shfl(s_l, i);
            float nm = __shfl(ds_l, i);
            acc = fmaf(H[(size_t)s * 64 + lane], nm, acc);
        }
    }
    out[(size_t)wid * 64 + lane] = fmaxf(fmaf(acc, dd, b[lane]), 0.f);
}

extern "C" void kernel_launch(void* const* d_in, const int* in_sizes, int n_in,
                              void* d_out, int out_size, void* d_ws, size_t ws_size,
                              hipStream_t stream) {
    const float* feat = (const float*)d_in[0];
    const float* W1   = (const float*)d_in[1];
    const float* b1   = (const float*)d_in[2];
    const float* W2   = (const float*)d_in[3];
    const float* b2   = (const float*)d_in[4];
    const void*  edges = d_in[5];
    float* out = (float*)d_out;

    char* ws = (char*)d_ws;
    const size_t SZ_N = 200704;  // >= 50001 ints
    int*   partial = (int*)ws;                        // 64 ints
    int*   cnt     = (int*)(ws + 1024);               // memset target
    float* dinv    = (float*)(ws + 1024 + SZ_N);
    int*   off     = (int*)(ws + 1024 + 2 * SZ_N);    // 50001 ints
    int*   cursor  = (int*)(ws + 1024 + 3 * SZ_N);
    int*   csr_src = (int*)(ws + 1024 + 4 * SZ_N);                 // 3.2 MB
    float* H       = (float*)(ws + 1024 + 4 * SZ_N + (size_t)N_EDGES * 4);  // 12.8 MB

    const int NB_E = (N_EDGES + 255) / 256;
    const int NB_G = (N_NODES + 63) / 64;    // 782
    const int NB_W = (N_NODES * 64 + 255) / 256;

    hipMemsetAsync(cnt, 0, SZ_N, stream);
    deg_count<<<NB_E, 256, 0, stream>>>(edges, cnt);
    scan_local<<<NCH, 1024, 0, stream>>>(cnt, off, partial, dinv);
    scan_mid<<<1, 64, 0, stream>>>(partial);
    scan_add<<<NCH, 1024, 0, stream>>>(off, partial, cursor);

    // Layer 1 GEMM fused with the CSR scatter (disjoint block ranges).
    fused_scatter_gemm<IN_DIM><<<NB_SC + NB_G, 256, 0, stream>>>(
        edges, cursor, csr_src, feat, W1, H, NB_SC);
    agg_csr<<<NB_W, 256, 0, stream>>>(H, dinv, b1, off, csr_src, out);

    // Layer 2
    gemm_mfma<OUT_DIM><<<NB_G, 256, 0, stream>>>(out, W2, H);
    agg_csr<<<NB_W, 256, 0, stream>>>(H, dinv, b2, off, csr_src, out);
}

// Round 9
// 233.839 us; speedup vs baseline: 1.7602x; 1.7602x over previous
//
#include <hip/hip_runtime.h>
#include <hip/hip_bf16.h>

#define N_NODES 50000
#define N_EDGES 800000
#define IN_DIM  256
#define OUT_DIM 64
#define NCH     49    // ceil(50000/1024) scan chunks
#define NB_SC   3125  // 800000/256 scatter blocks

using bf16x8 = __attribute__((ext_vector_type(8))) __bf16;
using f32x4  = __attribute__((ext_vector_type(4))) float;
using u16x8  = __attribute__((ext_vector_type(8))) unsigned short;

// ---------------------------------------------------------------------------
// Inline edge-dtype probe (int64 vs int32), block-uniform result.
// ---------------------------------------------------------------------------
__device__ __forceinline__ int probe_is64(const void* edges, int* nz_s) {
    if (threadIdx.x == 0) *nz_s = 0;
    __syncthreads();
    if (((const unsigned int*)edges)[2 * threadIdx.x + 1] != 0u) *nz_s = 1;
    __syncthreads();
    return (*nz_s == 0);
}

// cnt[dst]++ per edge
__global__ void deg_count(const void* __restrict__ edges, int* __restrict__ cnt) {
    __shared__ int nz;
    int is64 = probe_is64(edges, &nz);
    int e = blockIdx.x * 256 + threadIdx.x;
    if (e >= N_EDGES) return;
    int d = is64 ? (int)((const long long*)edges)[(long long)N_EDGES + e]
                 : ((const int*)edges)[(long long)N_EDGES + e];
    atomicAdd(&cnt[d], 1);
}

// --------------------- hierarchical exclusive scan -------------------------
__global__ __launch_bounds__(1024) void scan_local(const int* __restrict__ cnt,
                                                   int* __restrict__ off,
                                                   int* __restrict__ partial,
                                                   float* __restrict__ dinv) {
    __shared__ int smem[1024];
    int i = blockIdx.x * 1024 + threadIdx.x;
    int v = (i < N_NODES) ? cnt[i] : 0;
    if (i < N_NODES) dinv[i] = rsqrtf((float)(v + 1));
    smem[threadIdx.x] = v;
    __syncthreads();
    for (int s = 1; s < 1024; s <<= 1) {
        int t = 0;
        if (threadIdx.x >= s) t = smem[threadIdx.x - s];
        __syncthreads();
        if (threadIdx.x >= s) smem[threadIdx.x] += t;
        __syncthreads();
    }
    int incl = smem[threadIdx.x];
    if (i < N_NODES) off[i] = incl - v;
    if (threadIdx.x == 1023) partial[blockIdx.x] = incl;
}

__global__ void scan_mid(int* __restrict__ partial) {
    int lane = threadIdx.x;
    int v = (lane < NCH) ? partial[lane] : 0;
    int orig = v;
    for (int s = 1; s < 64; s <<= 1) {
        int t = __shfl_up(v, s);
        if (lane >= s) v += t;
    }
    if (lane < NCH) partial[lane] = v - orig;
    if (lane == 63) partial[63] = v;
}

__global__ __launch_bounds__(1024) void scan_add(int* __restrict__ off,
                                                 const int* __restrict__ partial,
                                                 int* __restrict__ cursor) {
    int i = blockIdx.x * 1024 + threadIdx.x;
    if (i < N_NODES) {
        int o = off[i] + partial[blockIdx.x];
        off[i] = o;
        cursor[i] = o;
    }
    if (i == 0) off[N_NODES] = partial[63];
}

// ---------------------------------------------------------------------------
// MFMA split-bf16 GEMM body: H[N,64] = X[N,K] @ W[K,64], f32 in/out.
// x = hi + lo (bf16 pair); X@W = hi_a*hi_b + hi_a*lo_b + lo_a*hi_b (3 MFMA).
// 256 threads = 4 waves; block covers 64 rows; wave w owns col slice
// [w*16, w*16+16). s-loop FULLY unrolled: bhi[s]/blo[s]/av[] all static
// indices -> registers (rule #20: partial unroll put them in scratch, 6x).
// ---------------------------------------------------------------------------
__device__ __forceinline__ unsigned short bf16_rn(float x) {
    unsigned u = __float_as_uint(x);
    unsigned r = u + 0x7FFFu + ((u >> 16) & 1u);
    return (unsigned short)(r >> 16);
}

template <int K>
__device__ __forceinline__ void gemm_body(int gbid, const float* __restrict__ X,
                                          const float* __restrict__ W,
                                          float* __restrict__ H) {
    constexpr int NS = K / 32;
    const int lane = threadIdx.x & 63;
    const int wave = threadIdx.x >> 6;   // col tile 0..3
    const int lm   = lane & 15;
    const int kg   = lane >> 4;          // 0..3

    // B fragments (this wave's 16 cols), hi/lo split, registers only.
    bf16x8 bhi[NS], blo[NS];
#pragma unroll
    for (int s = 0; s < NS; ++s) {
        u16x8 hb, lb;
#pragma unroll
        for (int j = 0; j < 8; ++j) {
            float w = W[(size_t)(s * 32 + kg * 8 + j) * 64 + wave * 16 + lm];
            unsigned short h = bf16_rn(w);
            float res = w - __uint_as_float((unsigned)h << 16);
            hb[j] = h;
            lb[j] = bf16_rn(res);
        }
        union { u16x8 u; bf16x8 b; } ch, cl;
        ch.u = hb; cl.u = lb;
        bhi[s] = ch.b; blo[s] = cl.b;
    }

    const int r0 = gbid * 64;
    const float* xr[4];
#pragma unroll
    for (int m = 0; m < 4; ++m) {
        int r = r0 + m * 16 + lm;
        xr[m] = X + (size_t)((r < N_NODES) ? r : (N_NODES - 1)) * K;
    }

    f32x4 acc[4] = {};

#pragma unroll
    for (int s = 0; s < NS; ++s) {
#pragma unroll
        for (int m = 0; m < 4; ++m) {
            float4 a0 = *(const float4*)(xr[m] + s * 32 + kg * 8);
            float4 a1 = *(const float4*)(xr[m] + s * 32 + kg * 8 + 4);
            float av[8] = {a0.x, a0.y, a0.z, a0.w, a1.x, a1.y, a1.z, a1.w};
            u16x8 ha, la;
#pragma unroll
            for (int j = 0; j < 8; ++j) {
                unsigned short h = bf16_rn(av[j]);
                float res = av[j] - __uint_as_float((unsigned)h << 16);
                ha[j] = h;
                la[j] = bf16_rn(res);
            }
            union { u16x8 u; bf16x8 b; } ah, al;
            ah.u = ha; al.u = la;
            acc[m] = __builtin_amdgcn_mfma_f32_16x16x32_bf16(ah.b, bhi[s], acc[m], 0, 0, 0);
            acc[m] = __builtin_amdgcn_mfma_f32_16x16x32_bf16(ah.b, blo[s], acc[m], 0, 0, 0);
            acc[m] = __builtin_amdgcn_mfma_f32_16x16x32_bf16(al.b, bhi[s], acc[m], 0, 0, 0);
        }
    }

    const int c = wave * 16 + lm;
#pragma unroll
    for (int m = 0; m < 4; ++m) {
#pragma unroll
        for (int t = 0; t < 4; ++t) {
            int r = r0 + m * 16 + kg * 4 + t;
            if (r < N_NODES) H[(size_t)r * 64 + c] = acc[m][t];
        }
    }
}

// ---------------------------------------------------------------------------
// Fused: blocks [0, nsc) scatter edges into CSR (HBM-write-bound);
// blocks [nsc, ...) run gemm1 (compute-bound). Overlap hides gemm1.
// ---------------------------------------------------------------------------
template <int K>
__global__ __launch_bounds__(256) void fused_scatter_gemm(const void* __restrict__ edges,
                                                          int* __restrict__ cursor,
                                                          int* __restrict__ csr_src,
                                                          const float* __restrict__ X,
                                                          const float* __restrict__ W,
                                                          float* __restrict__ H,
                                                          int nsc) {
    if ((int)blockIdx.x < nsc) {
        __shared__ int nz;
        int is64 = probe_is64(edges, &nz);
        int e = blockIdx.x * 256 + threadIdx.x;
        if (e >= N_EDGES) return;
        int s, d;
        if (is64) {
            s = (int)((const long long*)edges)[e];
            d = (int)((const long long*)edges)[(long long)N_EDGES + e];
        } else {
            s = ((const int*)edges)[e];
            d = ((const int*)edges)[(long long)N_EDGES + e];
        }
        int pos = atomicAdd(&cursor[d], 1);
        csr_src[pos] = s;
    } else {
        gemm_body<K>((int)blockIdx.x - nsc, X, W, H);
    }
}

template <int K>
__global__ __launch_bounds__(256) void gemm_mfma(const float* __restrict__ X,
                                                 const float* __restrict__ W,
                                                 float* __restrict__ H) {
    gemm_body<K>((int)blockIdx.x, X, W, H);
}

// ---------------------------------------------------------------------------
// Gather-aggregate: one wave per dst node, lane = column.
// out = relu( (Σ_s H[s]*dinv[s] + H[d]*dd) * dd + b )
// ---------------------------------------------------------------------------
__global__ __launch_bounds__(256) void agg_csr(const float* __restrict__ H,
                                               const float* __restrict__ dinv,
                                               const float* __restrict__ b,
                                               const int* __restrict__ off,
                                               const int* __restrict__ csr_src,
                                               float* __restrict__ out) {
    int wid  = (blockIdx.x * 256 + threadIdx.x) >> 6;
    int lane = threadIdx.x & 63;
    if (wid >= N_NODES) return;
    float dd = dinv[wid];
    float acc = H[(size_t)wid * 64 + lane] * dd;
    int beg = off[wid], end = off[wid + 1];
    for (int k0 = beg; k0 < end; k0 += 64) {
        int myk = k0 + lane;
        int   s_l  = (myk < end) ? csr_src[myk] : 0;
        float ds_l = (myk < end) ? dinv[s_l] : 0.f;
        int cnt = min(64, end - k0);
        int i = 0;
        for (; i + 8 <= cnt; i += 8) {
            float v[8], nm[8];
#pragma unroll
            for (int jj = 0; jj < 8; ++jj) {
                int s  = __shfl(s_l, i + jj);
                nm[jj] = __shfl(ds_l, i + jj);
                v[jj]  = H[(size_t)s * 64 + lane];
            }
#pragma unroll
            for (int jj = 0; jj < 8; ++jj) acc = fmaf(v[jj], nm[jj], acc);
        }
        for (; i < cnt; ++i) {
            int   s  = __shfl(s_l, i);
            float nm = __shfl(ds_l, i);
            acc = fmaf(H[(size_t)s * 64 + lane], nm, acc);
        }
    }
    out[(size_t)wid * 64 + lane] = fmaxf(fmaf(acc, dd, b[lane]), 0.f);
}

extern "C" void kernel_launch(void* const* d_in, const int* in_sizes, int n_in,
                              void* d_out, int out_size, void* d_ws, size_t ws_size,
                              hipStream_t stream) {
    const float* feat = (const float*)d_in[0];
    const float* W1   = (const float*)d_in[1];
    const float* b1   = (const float*)d_in[2];
    const float* W2   = (const float*)d_in[3];
    const float* b2   = (const float*)d_in[4];
    const void*  edges = d_in[5];
    float* out = (float*)d_out;

    char* ws = (char*)d_ws;
    const size_t SZ_N = 200704;  // >= 50001 ints
    int*   partial = (int*)ws;                        // 64 ints
    int*   cnt     = (int*)(ws + 1024);               // memset target
    float* dinv    = (float*)(ws + 1024 + SZ_N);
    int*   off     = (int*)(ws + 1024 + 2 * SZ_N);    // 50001 ints
    int*   cursor  = (int*)(ws + 1024 + 3 * SZ_N);
    int*   csr_src = (int*)(ws + 1024 + 4 * SZ_N);                 // 3.2 MB
    float* H       = (float*)(ws + 1024 + 4 * SZ_N + (size_t)N_EDGES * 4);  // 12.8 MB

    const int NB_E = (N_EDGES + 255) / 256;
    const int NB_G = (N_NODES + 63) / 64;    // 782
    const int NB_W = (N_NODES * 64 + 255) / 256;

    hipMemsetAsync(cnt, 0, SZ_N, stream);
    deg_count<<<NB_E, 256, 0, stream>>>(edges, cnt);
    scan_local<<<NCH, 1024, 0, stream>>>(cnt, off, partial, dinv);
    scan_mid<<<1, 64, 0, stream>>>(partial);
    scan_add<<<NCH, 1024, 0, stream>>>(off, partial, cursor);

    // Layer 1 GEMM fused with the CSR scatter (disjoint block ranges).
    fused_scatter_gemm<IN_DIM><<<NB_SC + NB_G, 256, 0, stream>>>(
        edges, cursor, csr_src, feat, W1, H, NB_SC);
    agg_csr<<<NB_W, 256, 0, stream>>>(H, dinv, b1, off, csr_src, out);

    // Layer 2
    gemm_mfma<OUT_DIM><<<NB_G, 256, 0, stream>>>(out, W2, H);
    agg_csr<<<NB_W, 256, 0, stream>>>(H, dinv, b2, off, csr_src, out);
}

// Round 10
// 208.651 us; speedup vs baseline: 1.9727x; 1.1207x over previous
//
#include <hip/hip_runtime.h>
#include <hip/hip_bf16.h>

#define N_NODES 50000
#define N_EDGES 800000
#define IN_DIM  256
#define OUT_DIM 64
#define NCH     49     // ceil(50000/1024) scan chunks
#define NRANGE  8      // XCD dst-range partitions
#define RSPAN   6250   // 50000/8
#define CHUNK   2048
#define NCHK    391    // ceil(800000/2048)

using bf16x8 = __attribute__((ext_vector_type(8))) __bf16;
using f32x4  = __attribute__((ext_vector_type(4))) float;
using u32x4  = __attribute__((ext_vector_type(4))) unsigned int;

// ---------------------------------------------------------------------------
// Edge dtype probe (int64 vs int32), block-uniform result.
// ---------------------------------------------------------------------------
__device__ __forceinline__ int probe_is64(const void* edges, int* nz_s) {
    if (threadIdx.x == 0) *nz_s = 0;
    __syncthreads();
    if (((const unsigned int*)edges)[2 * threadIdx.x + 1] != 0u) *nz_s = 1;
    __syncthreads();
    return (*nz_s == 0);
}

// Normalize edges to int32 arrays + fused degree count.
__global__ void edge_norm_deg(const void* __restrict__ edges, int* __restrict__ src32,
                              int* __restrict__ dst32, int* __restrict__ cnt) {
    __shared__ int nz;
    int is64 = probe_is64(edges, &nz);
    int e = blockIdx.x * 256 + threadIdx.x;
    if (e >= N_EDGES) return;
    int s, d;
    if (is64) {
        s = (int)((const long long*)edges)[e];
        d = (int)((const long long*)edges)[(long long)N_EDGES + e];
    } else {
        s = ((const int*)edges)[e];
        d = ((const int*)edges)[(long long)N_EDGES + e];
    }
    src32[e] = s;
    dst32[e] = d;
    atomicAdd(&cnt[d], 1);
}

// --------------------- hierarchical exclusive scan -------------------------
__global__ __launch_bounds__(1024) void scan_local(const int* __restrict__ cnt,
                                                   int* __restrict__ off,
                                                   int* __restrict__ partial,
                                                   float* __restrict__ dinv) {
    __shared__ int smem[1024];
    int i = blockIdx.x * 1024 + threadIdx.x;
    int v = (i < N_NODES) ? cnt[i] : 0;
    if (i < N_NODES) dinv[i] = rsqrtf((float)(v + 1));
    smem[threadIdx.x] = v;
    __syncthreads();
    for (int s = 1; s < 1024; s <<= 1) {
        int t = 0;
        if (threadIdx.x >= s) t = smem[threadIdx.x - s];
        __syncthreads();
        if (threadIdx.x >= s) smem[threadIdx.x] += t;
        __syncthreads();
    }
    int incl = smem[threadIdx.x];
    if (i < N_NODES) off[i] = incl - v;
    if (threadIdx.x == 1023) partial[blockIdx.x] = incl;
}

__global__ void scan_mid(int* __restrict__ partial) {
    int lane = threadIdx.x;
    int v = (lane < NCH) ? partial[lane] : 0;
    int orig = v;
    for (int s = 1; s < 64; s <<= 1) {
        int t = __shfl_up(v, s);
        if (lane >= s) v += t;
    }
    if (lane < NCH) partial[lane] = v - orig;
    if (lane == 63) partial[63] = v;
}

__global__ __launch_bounds__(1024) void scan_add(int* __restrict__ off,
                                                 const int* __restrict__ partial,
                                                 int* __restrict__ cursor) {
    int i = blockIdx.x * 1024 + threadIdx.x;
    if (i < N_NODES) {
        int o = off[i] + partial[blockIdx.x];
        off[i] = o;
        cursor[i] = o;
    }
    if (i == 0) off[N_NODES] = partial[63];
}

// ---------------------------------------------------------------------------
// XCD-partitioned scatter: block (range = blockIdx&7) handles only dst in
// [range*RSPAN, ...+RSPAN). Its CSR window (~400 KB) stays resident in that
// XCD's L2 -> 4B stores merge into full-line writebacks (kills the 52.8 MB
// random-write amplification). dst32/src32 re-reads hit L3. Correctness is
// independent of the actual block->XCD mapping.
// ---------------------------------------------------------------------------
__global__ __launch_bounds__(256) void scatter_xcd(const int* __restrict__ dst32,
                                                   const int* __restrict__ src32,
                                                   int* __restrict__ cursor,
                                                   int* __restrict__ csr_src) {
    const int range = blockIdx.x & (NRANGE - 1);
    const int chunk = blockIdx.x >> 3;
    const int rlo = range * RSPAN, rhi = rlo + RSPAN;
    const int base = chunk * CHUNK;
#pragma unroll
    for (int j = 0; j < CHUNK / 256; ++j) {
        int e = base + j * 256 + (int)threadIdx.x;
        if (e < N_EDGES) {
            int d = dst32[e];
            if (d >= rlo && d < rhi) {
                int pos = atomicAdd(&cursor[d], 1);
                csr_src[pos] = src32[e];
            }
        }
    }
}

// ---------------------------------------------------------------------------
// MFMA split-bf16 GEMM: H[N,64] = X[N,K] @ W[K,64], f32 in/out.
// x = hi + lo via TRUNCATION split (hi = bits>>16; x-hi exact; lo = trunc):
// ~4 VALU/elem. X@W = hi_a*hi_b + hi_a*lo_b + lo_a*hi_b (3 MFMA), rel err
// ~2^-16. 256 thr = 4 waves; wave w owns cols [w*16,w*16+16), 4 row-tiles.
// All loops fully unrolled -> fragments in registers (rule #20).
// ---------------------------------------------------------------------------
union BFu { u32x4 u; bf16x8 b; };

__device__ __forceinline__ void split_pack(float x0, float x1,
                                           unsigned& hi, unsigned& lo) {
    unsigned u0 = __float_as_uint(x0), u1 = __float_as_uint(x1);
    hi = (u1 & 0xFFFF0000u) | (u0 >> 16);
    float h0 = __uint_as_float(u0 & 0xFFFF0000u);
    float h1 = __uint_as_float(u1 & 0xFFFF0000u);
    unsigned r0 = __float_as_uint(x0 - h0);
    unsigned r1 = __float_as_uint(x1 - h1);
    lo = (r1 & 0xFFFF0000u) | (r0 >> 16);
}

template <int K>
__device__ __forceinline__ void gemm_body(int gbid, const float* __restrict__ X,
                                          const float* __restrict__ W,
                                          float* __restrict__ H) {
    constexpr int NS = K / 32;
    const int lane = threadIdx.x & 63;
    const int wave = threadIdx.x >> 6;   // col tile 0..3
    const int lm   = lane & 15;
    const int kg   = lane >> 4;          // 0..3

    BFu bhi[NS], blo[NS];
#pragma unroll
    for (int s = 0; s < NS; ++s) {
#pragma unroll
        for (int jp = 0; jp < 4; ++jp) {
            float w0 = W[(size_t)(s * 32 + kg * 8 + 2 * jp)     * 64 + wave * 16 + lm];
            float w1 = W[(size_t)(s * 32 + kg * 8 + 2 * jp + 1) * 64 + wave * 16 + lm];
            unsigned h, l;
            split_pack(w0, w1, h, l);
            bhi[s].u[jp] = h;
            blo[s].u[jp] = l;
        }
    }

    const int r0 = gbid * 64;
    const float* xr[4];
#pragma unroll
    for (int m = 0; m < 4; ++m) {
        int r = r0 + m * 16 + lm;
        xr[m] = X + (size_t)((r < N_NODES) ? r : (N_NODES - 1)) * K;
    }

    f32x4 acc[4] = {};

#pragma unroll
    for (int s = 0; s < NS; ++s) {
#pragma unroll
        for (int m = 0; m < 4; ++m) {
            float4 a0 = *(const float4*)(xr[m] + s * 32 + kg * 8);
            float4 a1 = *(const float4*)(xr[m] + s * 32 + kg * 8 + 4);
            BFu ah, al;
            unsigned h, l;
            split_pack(a0.x, a0.y, h, l); ah.u[0] = h; al.u[0] = l;
            split_pack(a0.z, a0.w, h, l); ah.u[1] = h; al.u[1] = l;
            split_pack(a1.x, a1.y, h, l); ah.u[2] = h; al.u[2] = l;
            split_pack(a1.z, a1.w, h, l); ah.u[3] = h; al.u[3] = l;
            acc[m] = __builtin_amdgcn_mfma_f32_16x16x32_bf16(ah.b, bhi[s].b, acc[m], 0, 0, 0);
            acc[m] = __builtin_amdgcn_mfma_f32_16x16x32_bf16(ah.b, blo[s].b, acc[m], 0, 0, 0);
            acc[m] = __builtin_amdgcn_mfma_f32_16x16x32_bf16(al.b, bhi[s].b, acc[m], 0, 0, 0);
        }
    }

    const int c = wave * 16 + lm;
#pragma unroll
    for (int m = 0; m < 4; ++m) {
#pragma unroll
        for (int t = 0; t < 4; ++t) {
            int r = r0 + m * 16 + kg * 4 + t;
            if (r < N_NODES) H[(size_t)r * 64 + c] = acc[m][t];
        }
    }
}

template <int K>
__global__ __launch_bounds__(256) void gemm_mfma(const float* __restrict__ X,
                                                 const float* __restrict__ W,
                                                 float* __restrict__ H) {
    gemm_body<K>((int)blockIdx.x, X, W, H);
}

// ---------------------------------------------------------------------------
// Gather-aggregate: one wave per dst node, lane = column.
// out = relu( (Σ_s H[s]*dinv[s] + H[d]*dd) * dd + b )
// ---------------------------------------------------------------------------
__global__ __launch_bounds__(256) void agg_csr(const float* __restrict__ H,
                                               const float* __restrict__ dinv,
                                               const float* __restrict__ b,
                                               const int* __restrict__ off,
                                               const int* __restrict__ csr_src,
                                               float* __restrict__ out) {
    int wid  = (blockIdx.x * 256 + threadIdx.x) >> 6;
    int lane = threadIdx.x & 63;
    if (wid >= N_NODES) return;
    float dd = dinv[wid];
    float acc = H[(size_t)wid * 64 + lane] * dd;
    int beg = off[wid], end = off[wid + 1];
    for (int k0 = beg; k0 < end; k0 += 64) {
        int myk = k0 + lane;
        int   s_l  = (myk < end) ? csr_src[myk] : 0;
        float ds_l = (myk < end) ? dinv[s_l] : 0.f;
        int cnt = min(64, end - k0);
        int i = 0;
        for (; i + 8 <= cnt; i += 8) {
            float v[8], nm[8];
#pragma unroll
            for (int jj = 0; jj < 8; ++jj) {
                int s  = __shfl(s_l, i + jj);
                nm[jj] = __shfl(ds_l, i + jj);
                v[jj]  = H[(size_t)s * 64 + lane];
            }
#pragma unroll
            for (int jj = 0; jj < 8; ++jj) acc = fmaf(v[jj], nm[jj], acc);
        }
        for (; i < cnt; ++i) {
            int   s  = __shfl(s_l, i);
            float nm = __shfl(ds_l, i);
            acc = fmaf(H[(size_t)s * 64 + lane], nm, acc);
        }
    }
    out[(size_t)wid * 64 + lane] = fmaxf(fmaf(acc, dd, b[lane]), 0.f);
}

extern "C" void kernel_launch(void* const* d_in, const int* in_sizes, int n_in,
                              void* d_out, int out_size, void* d_ws, size_t ws_size,
                              hipStream_t stream) {
    const float* feat = (const float*)d_in[0];
    const float* W1   = (const float*)d_in[1];
    const float* b1   = (const float*)d_in[2];
    const float* W2   = (const float*)d_in[3];
    const float* b2   = (const float*)d_in[4];
    const void*  edges = d_in[5];
    float* out = (float*)d_out;

    char* ws = (char*)d_ws;
    const size_t SZ_N = 200704;   // >= 50001 ints
    const size_t SZ_E = (size_t)N_EDGES * 4;
    int*   partial = (int*)ws;                        // 64 ints
    int*   cnt     = (int*)(ws + 1024);               // memset target
    float* dinv    = (float*)(ws + 1024 + SZ_N);
    int*   off     = (int*)(ws + 1024 + 2 * SZ_N);    // 50001 ints
    int*   cursor  = (int*)(ws + 1024 + 3 * SZ_N);
    int*   src32   = (int*)(ws + 1024 + 4 * SZ_N);               // 3.2 MB
    int*   dst32   = (int*)(ws + 1024 + 4 * SZ_N + SZ_E);        // 3.2 MB
    int*   csr_src = (int*)(ws + 1024 + 4 * SZ_N + 2 * SZ_E);    // 3.2 MB
    float* H       = (float*)(ws + 1024 + 4 * SZ_N + 3 * SZ_E);  // 12.8 MB

    const int NB_E = (N_EDGES + 255) / 256;
    const int NB_G = (N_NODES + 63) / 64;    // 782
    const int NB_W = (N_NODES * 64 + 255) / 256;

    hipMemsetAsync(cnt, 0, SZ_N, stream);
    edge_norm_deg<<<NB_E, 256, 0, stream>>>(edges, src32, dst32, cnt);
    scan_local<<<NCH, 1024, 0, stream>>>(cnt, off, partial, dinv);
    scan_mid<<<1, 64, 0, stream>>>(partial);
    scan_add<<<NCH, 1024, 0, stream>>>(off, partial, cursor);
    scatter_xcd<<<NRANGE * NCHK, 256, 0, stream>>>(dst32, src32, cursor, csr_src);

    // Layer 1
    gemm_mfma<IN_DIM><<<NB_G, 256, 0, stream>>>(feat, W1, H);
    agg_csr<<<NB_W, 256, 0, stream>>>(H, dinv, b1, off, csr_src, out);

    // Layer 2 (out holds relu'd z1)
    gemm_mfma<OUT_DIM><<<NB_G, 256, 0, stream>>>(out, W2, H);
    agg_csr<<<NB_W, 256, 0, stream>>>(H, dinv, b2, off, csr_src, out);
}